// Round 1
// baseline (1434.871 us; speedup 1.0000x reference)
//
#include <hip/hip_runtime.h>

#define N_NODES 50000
#define N_EDGES 800000
#define DIM 128   // IN_DIM == HEADS*HEAD_DIM == 128
#define HEADS 8

// ---------------- workspace layout (in 4-byte words) ----------------
// Q       : [0,            6,400,000)   float  N*128
// K       : [6,400,000,   12,800,000)   float
// V       : [12,800,000,  19,200,000)   float
// S       : [19,200,000,  25,600,000)   float  E*8  (per-edge-head exp score)
// counts  : [25,600,000,  +50,001)      int
// offsets : [25,650,008,  +50,001)      int
// cursor  : [25,700,016,  +50,000)      int
// eidx    : [25,750,016,  +800,000)     int
// total ≈ 106.2 MB

__global__ void k_zero_counts(int* __restrict__ counts) {
  int i = blockIdx.x * 256 + threadIdx.x;
  if (i < N_NODES) counts[i] = 0;
}

__global__ void k_count(const int* __restrict__ dst, int* __restrict__ counts) {
  int e = blockIdx.x * 256 + threadIdx.x;
  if (e < N_EDGES) atomicAdd(&counts[dst[e]], 1);
}

// single-block exclusive scan over 50000 counts -> offsets, cursor
__global__ void k_scan(const int* __restrict__ counts, int* __restrict__ offsets,
                       int* __restrict__ cursor) {
  __shared__ int lds[1024];
  const int CH = 49;  // 1024*49 = 50176 >= 50000
  int t = threadIdx.x;
  int base = t * CH;
  int sum = 0;
  for (int q = 0; q < CH; ++q) {
    int idx = base + q;
    if (idx < N_NODES) sum += counts[idx];
  }
  lds[t] = sum;
  __syncthreads();
  for (int off = 1; off < 1024; off <<= 1) {
    int v = (t >= off) ? lds[t - off] : 0;
    __syncthreads();
    lds[t] += v;
    __syncthreads();
  }
  int run = (t > 0) ? lds[t - 1] : 0;
  for (int q = 0; q < CH; ++q) {
    int idx = base + q;
    if (idx < N_NODES) {
      offsets[idx] = run;
      cursor[idx] = run;
      run += counts[idx];
    }
  }
  if (t == 1023) offsets[N_NODES] = lds[1023];
}

__global__ void k_fill(const int* __restrict__ dst, int* __restrict__ cursor,
                       int* __restrict__ eidx) {
  int e = blockIdx.x * 256 + threadIdx.x;
  if (e < N_EDGES) {
    int pos = atomicAdd(&cursor[dst[e]], 1);
    eidx[pos] = e;
  }
}

// out[n, :] = h[n, :] @ W + bias       tile: 128 nodes x 128 cols, K=128
// A staged transposed in LDS (pad 132, conflict-free float4 reads);
// W read from global (64KB, L1/L2-resident).  8x8 acc per thread.
__global__ __launch_bounds__(256) void k_node_proj(
    const float* __restrict__ h, const float* __restrict__ W,
    const float* __restrict__ bias, float* __restrict__ out) {
  __shared__ float hT[DIM][132];
  int t = threadIdx.x;
  int n0 = blockIdx.x * 128;
  for (int it = 0; it < 16; ++it) {
    int row = it * 8 + (t >> 5);
    int node = min(n0 + row, N_NODES - 1);
    int c = (t & 31) * 4;
    const float4 v = *(const float4*)(h + (size_t)node * DIM + c);
    hT[c + 0][row] = v.x; hT[c + 1][row] = v.y;
    hT[c + 2][row] = v.z; hT[c + 3][row] = v.w;
  }
  __syncthreads();
  int tx = t & 15;   // cols tx*8 .. tx*8+7
  int ng = t >> 4;   // nodes ng*8 .. ng*8+7
  float acc[8][8];
#pragma unroll
  for (int i = 0; i < 8; ++i)
#pragma unroll
    for (int j = 0; j < 8; ++j) acc[i][j] = 0.f;

#pragma unroll 4
  for (int k = 0; k < DIM; ++k) {
    float4 a0 = *(const float4*)&hT[k][ng * 8];
    float4 a1 = *(const float4*)&hT[k][ng * 8 + 4];
    const float* wr = W + k * DIM + tx * 8;
    float4 b0 = *(const float4*)wr;
    float4 b1 = *(const float4*)(wr + 4);
    float av[8] = {a0.x, a0.y, a0.z, a0.w, a1.x, a1.y, a1.z, a1.w};
    float bv[8] = {b0.x, b0.y, b0.z, b0.w, b1.x, b1.y, b1.z, b1.w};
#pragma unroll
    for (int i = 0; i < 8; ++i)
#pragma unroll
      for (int j = 0; j < 8; ++j) acc[i][j] += av[i] * bv[j];
  }
  float bb[8];
#pragma unroll
  for (int j = 0; j < 8; ++j) bb[j] = bias[tx * 8 + j];
#pragma unroll
  for (int i = 0; i < 8; ++i) {
    int node = n0 + ng * 8 + i;
    if (node < N_NODES) {
      float4 o0 = {acc[i][0] + bb[0], acc[i][1] + bb[1], acc[i][2] + bb[2], acc[i][3] + bb[3]};
      float4 o1 = {acc[i][4] + bb[4], acc[i][5] + bb[5], acc[i][6] + bb[6], acc[i][7] + bb[7]};
      float* op = out + (size_t)node * DIM + tx * 8;
      *(float4*)op = o0;
      *(float4*)(op + 4) = o1;
    }
  }
}

// per 128-edge tile: proj = e@We + be, score = K[src]*Q[dst]*0.25*proj,
// e_out = score, s = exp(clamp(sum_head(score))) -> S
__global__ __launch_bounds__(256) void k_edge(
    const float* __restrict__ e, const int* __restrict__ src,
    const int* __restrict__ dst, const float* __restrict__ We,
    const float* __restrict__ be, const float* __restrict__ Qn,
    const float* __restrict__ Kn, float* __restrict__ e_out,
    float* __restrict__ s_out) {
  __shared__ float eT[DIM][132];
  __shared__ int sS[128];
  __shared__ int sD[128];
  int t = threadIdx.x;
  int e0 = blockIdx.x * 128;
  for (int it = 0; it < 16; ++it) {
    int row = it * 8 + (t >> 5);
    int c = (t & 31) * 4;
    const float4 v = *(const float4*)(e + (size_t)(e0 + row) * DIM + c);
    eT[c + 0][row] = v.x; eT[c + 1][row] = v.y;
    eT[c + 2][row] = v.z; eT[c + 3][row] = v.w;
  }
  if (t < 128) sS[t] = src[e0 + t];
  else if (t < 256) sD[t - 128] = dst[e0 + t - 128];
  __syncthreads();

  int tx = t & 15;   // cols tx*8..+7
  int eg = t >> 4;   // edges eg*8..+7 (tile-local)
  float acc[8][8];
#pragma unroll
  for (int i = 0; i < 8; ++i)
#pragma unroll
    for (int j = 0; j < 8; ++j) acc[i][j] = 0.f;

#pragma unroll 4
  for (int k = 0; k < DIM; ++k) {
    float4 a0 = *(const float4*)&eT[k][eg * 8];
    float4 a1 = *(const float4*)&eT[k][eg * 8 + 4];
    const float* wr = We + k * DIM + tx * 8;
    float4 b0 = *(const float4*)wr;
    float4 b1 = *(const float4*)(wr + 4);
    float av[8] = {a0.x, a0.y, a0.z, a0.w, a1.x, a1.y, a1.z, a1.w};
    float bv[8] = {b0.x, b0.y, b0.z, b0.w, b1.x, b1.y, b1.z, b1.w};
#pragma unroll
    for (int i = 0; i < 8; ++i)
#pragma unroll
      for (int j = 0; j < 8; ++j) acc[i][j] += av[i] * bv[j];
  }

  float bb[8];
#pragma unroll
  for (int j = 0; j < 8; ++j) bb[j] = be[tx * 8 + j];

#pragma unroll
  for (int i = 0; i < 8; ++i) {
    int erow = eg * 8 + i;
    int eid = e0 + erow;
    int s_ = sS[erow];
    int d_ = sD[erow];
    const float* kp = Kn + (size_t)s_ * DIM + tx * 8;
    const float* qp = Qn + (size_t)d_ * DIM + tx * 8;
    float4 k0 = *(const float4*)kp;
    float4 k1 = *(const float4*)(kp + 4);
    float4 q0 = *(const float4*)qp;
    float4 q1 = *(const float4*)(qp + 4);
    float kv[8] = {k0.x, k0.y, k0.z, k0.w, k1.x, k1.y, k1.z, k1.w};
    float qv[8] = {q0.x, q0.y, q0.z, q0.w, q1.x, q1.y, q1.z, q1.w};
    float sc[8];
    float sum = 0.f;
#pragma unroll
    for (int j = 0; j < 8; ++j) {
      float proj = acc[i][j] + bb[j];
      sc[j] = kv[j] * qv[j] * 0.25f * proj;
      sum += sc[j];
    }
    float* eo = e_out + (size_t)eid * DIM + tx * 8;
    float4 o0 = {sc[0], sc[1], sc[2], sc[3]};
    float4 o1 = {sc[4], sc[5], sc[6], sc[7]};
    *(float4*)eo = o0;
    *(float4*)(eo + 4) = o1;
    // pair-sum across the two lanes of this head (tx even/odd are adjacent lanes)
    sum += __shfl_xor(sum, 1);
    float sv = expf(fminf(fmaxf(sum, -5.f), 5.f));
    if ((tx & 1) == 0) s_out[(size_t)eid * 8 + (tx >> 1)] = sv;
  }
}

// gather-side aggregation over dst-CSR: no float atomics
__global__ __launch_bounds__(256) void k_aggregate(
    const float* __restrict__ Vn, const float* __restrict__ s_arr,
    const int* __restrict__ src, const int* __restrict__ offsets,
    const int* __restrict__ eidx, float* __restrict__ h_out) {
  int t = threadIdx.x;
  int n = blockIdx.x * 2 + (t >> 7);
  int j = t & 127;
  int head = j >> 4;
  int beg = offsets[n];
  int end = offsets[n + 1];
  float sv = 0.f, z = 0.f;
#pragma unroll 2
  for (int p = beg; p < end; ++p) {
    int ei = eidx[p];
    float sw = s_arr[(size_t)ei * 8 + head];
    int sn = src[ei];
    sv += sw * Vn[(size_t)sn * DIM + j];
    z += sw;
  }
  h_out[(size_t)n * DIM + j] = sv / (z + 1e-6f);
}

extern "C" void kernel_launch(void* const* d_in, const int* in_sizes, int n_in,
                              void* d_out, int out_size, void* d_ws, size_t ws_size,
                              hipStream_t stream) {
  const float* h  = (const float*)d_in[0];
  const float* e  = (const float*)d_in[1];
  const int* src  = (const int*)d_in[2];
  const int* dst  = (const int*)d_in[3];
  const float* Wq = (const float*)d_in[4];
  const float* bq = (const float*)d_in[5];
  const float* Wk = (const float*)d_in[6];
  const float* bk = (const float*)d_in[7];
  const float* Wv = (const float*)d_in[8];
  const float* bv = (const float*)d_in[9];
  const float* We = (const float*)d_in[10];
  const float* be = (const float*)d_in[11];

  float* ws = (float*)d_ws;
  float* Q = ws;
  float* K = ws + 6400000;
  float* V = ws + 12800000;
  float* S = ws + 19200000;
  int* counts  = (int*)(ws + 25600000);
  int* offsets = (int*)(ws + 25650008);
  int* cursor  = (int*)(ws + 25700016);
  int* eidx    = (int*)(ws + 25750016);

  float* h_out = (float*)d_out;
  float* e_out = h_out + (size_t)N_NODES * DIM;

  // CSR build (int atomics only)
  k_zero_counts<<<(N_NODES + 255) / 256, 256, 0, stream>>>(counts);
  k_count<<<(N_EDGES + 255) / 256, 256, 0, stream>>>(dst, counts);
  k_scan<<<1, 1024, 0, stream>>>(counts, offsets, cursor);
  k_fill<<<(N_EDGES + 255) / 256, 256, 0, stream>>>(dst, cursor, eidx);

  // node projections
  k_node_proj<<<391, 256, 0, stream>>>(h, Wq, bq, Q);
  k_node_proj<<<391, 256, 0, stream>>>(h, Wk, bk, K);
  k_node_proj<<<391, 256, 0, stream>>>(h, Wv, bv, V);

  // edge projection + scores + per-edge-head exp
  k_edge<<<N_EDGES / 128, 256, 0, stream>>>(e, src, dst, We, be, Q, K, e_out, S);

  // gather aggregation
  k_aggregate<<<N_NODES / 2, 256, 0, stream>>>(V, S, src, offsets, eidx, h_out);
}